// Round 4
// baseline (1742.825 us; speedup 1.0000x reference)
//
#include <hip/hip_runtime.h>
#include <hip/hip_bf16.h>
#include <cstdint>

// ---------------------------------------------------------------------------
// TransducerJoint: out[b,t,u,:] = tanh(f[b,t,:] + g[b,u,:]) @ W_joint + b_joint
// R3 -> R4: FUSED main kernel. A = tanh(f+g) is computed in-register per
// K-step (f,g are L2-resident, 3.4 MB total) and ds_written to LDS -- the
// 123 MB Abuf round-trip and the k_build_a kernel are gone. BM=128, BN=512
// (only 2x tanh recompute; VALU co-issues under MFMA), BK=32, double-buffered
// LDS (80 KB -> 2 blocks/CU, 4 waves/SIMD). B staged via global_load_lds with
// pre-permuted source chunks (rotate slot=(c+(r>>1))&3, conflict-free reads);
// A written directly at the swizzled slot. f/g loads issue before the MFMA
// cluster, tanh+ds_write after it (T14 issue-early/write-late).
// ---------------------------------------------------------------------------

typedef __attribute__((ext_vector_type(4))) float f32x4;
typedef __attribute__((ext_vector_type(8))) short s16x8;

#define B_ 4
#define T_ 300
#define U_ 100
#define DM 512
#define VOC 1024
#define M_MAIN (B_*T_*U_)       // 120000
#define M_ENC_PAD 1280          // 10 * 128 (valid 1200)
#define M_PRED_PAD 512          // 4 * 128 (valid 400)

__device__ __forceinline__ unsigned short f2bf(float x) {
  unsigned int u = __builtin_bit_cast(unsigned int, x);
  u += 0x7FFFu + ((u >> 16) & 1u);          // round-to-nearest-even
  return (unsigned short)(u >> 16);
}

__device__ __forceinline__ float fast_tanh(float x) {
  float e = __builtin_amdgcn_exp2f(x * 2.8853900817779268f);
  return fmaf(-2.0f, __builtin_amdgcn_rcpf(e + 1.0f), 1.0f);
}

__device__ __forceinline__ void gload_lds16(const void* g, void* l) {
  __builtin_amdgcn_global_load_lds(
      (const __attribute__((address_space(1))) void*)g,
      (__attribute__((address_space(3))) void*)l, 16, 0, 0);
}

// ---------------------------------------------------------------------------
__global__ void k_cvtpad(const float* __restrict__ enc, const float* __restrict__ pred,
                         unsigned short* __restrict__ encb, unsigned short* __restrict__ predb)
{
  int idx = blockIdx.x * 256 + threadIdx.x;
  const int encCh = M_ENC_PAD * 64;
  const float* src; unsigned short* dst; int Mv; int id2;
  if (idx < encCh) { src = enc; dst = encb; Mv = B_*T_; id2 = idx; }
  else            { id2 = idx - encCh; src = pred; dst = predb; Mv = B_*U_; }
  int r = id2 >> 6, k = (id2 & 63) * 8;
  s16x8 v;
  if (r < Mv) {
    f32x4 a = *(const f32x4*)(src + r*DM + k);
    f32x4 b = *(const f32x4*)(src + r*DM + k + 4);
#pragma unroll
    for (int j = 0; j < 4; ++j) { v[j] = (short)f2bf(a[j]); v[4+j] = (short)f2bf(b[j]); }
  } else {
#pragma unroll
    for (int j = 0; j < 8; ++j) v[j] = 0;
  }
  *(s16x8*)(dst + (long)id2 * 8) = v;
}

// ---------------------------------------------------------------------------
__global__ void k_transpose3(const float* __restrict__ We, const float* __restrict__ Wp,
                             const float* __restrict__ Wj,
                             unsigned short* __restrict__ WeT, unsigned short* __restrict__ WpT,
                             unsigned short* __restrict__ WjT)
{
  __shared__ float tile[32][33];
  const float* src; unsigned short* dst; int Ccols;
  const int R = 512;
  if (blockIdx.z == 0)      { src = We; dst = WeT; Ccols = 512; }
  else if (blockIdx.z == 1) { src = Wp; dst = WpT; Ccols = 512; }
  else                      { src = Wj; dst = WjT; Ccols = 1024; }
  int bx = blockIdx.x, by = blockIdx.y;
  if (bx * 32 >= Ccols) return;
  int x = threadIdx.x & 31, y = threadIdx.x >> 5;
  int c0 = bx * 32, r0 = by * 32;
#pragma unroll
  for (int i = 0; i < 4; ++i)
    tile[y + i*8][x] = src[(r0 + y + i*8) * Ccols + c0 + x];
  __syncthreads();
#pragma unroll
  for (int i = 0; i < 4; ++i)
    dst[(c0 + y + i*8) * R + r0 + x] = f2bf(tile[x][y + i*8]);
}

// ---------------------------------------------------------------------------
// 128x128 gemm body (small f/g GEMMs only).
// ---------------------------------------------------------------------------
__device__ __forceinline__ void gemm_body(const unsigned short* __restrict__ A,
                                          const unsigned short* __restrict__ Bt,
                                          const float* __restrict__ bias,
                                          float* __restrict__ C,
                                          int Mvalid, int ldc, int mt, int nt)
{
  __shared__ unsigned short lza[128*64];
  __shared__ unsigned short lzb[128*64];
  const int tid  = threadIdx.x;
  const int wave = tid >> 6;
  const int lane = tid & 63;
  const int row0 = mt * 128;
  const int col0 = nt * 128;
  const int wm = (wave >> 1) * 64;
  const int wn = (wave & 1) * 64;

  const int rloc0 = wave*32 + (lane >> 3);
  const int srcc  = (lane & 7) ^ (rloc0 & 7);
  const unsigned short* gA = A  + (row0 + rloc0)*DM + srcc*8;
  const unsigned short* gB = Bt + (col0 + rloc0)*DM + srcc*8;
  unsigned short* ldsA = &lza[(wave*32)*64];
  unsigned short* ldsB = &lzb[(wave*32)*64];

  f32x4 acc[4][4] = {};

  for (int kt = 0; kt < DM/64; ++kt) {
    __syncthreads();
#pragma unroll
    for (int i = 0; i < 4; ++i) {
      gload_lds16(gA + i*8*DM, ldsA + i*8*64);
      gload_lds16(gB + i*8*DM, ldsB + i*8*64);
    }
    gA += 64; gB += 64;
    __syncthreads();
#pragma unroll
    for (int kk = 0; kk < 2; ++kk) {
      s16x8 af[4], bfr[4];
#pragma unroll
      for (int m = 0; m < 4; ++m) {
        int r = wm + m*16 + (lane & 15);
        int c = (kk*4 + (lane >> 4)) ^ (r & 7);
        af[m] = *(const s16x8*)&lza[r*64 + c*8];
      }
#pragma unroll
      for (int n = 0; n < 4; ++n) {
        int r = wn + n*16 + (lane & 15);
        int c = (kk*4 + (lane >> 4)) ^ (r & 7);
        bfr[n] = *(const s16x8*)&lzb[r*64 + c*8];
      }
#pragma unroll
      for (int m = 0; m < 4; ++m)
#pragma unroll
        for (int n = 0; n < 4; ++n)
          acc[m][n] = __builtin_amdgcn_mfma_f32_16x16x32_bf16(af[m], bfr[n], acc[m][n], 0, 0, 0);
    }
  }

  const int cl = lane & 15, rq = (lane >> 4) * 4;
#pragma unroll
  for (int n = 0; n < 4; ++n) {
    int col = col0 + wn + n*16 + cl;
    float bv = bias[col];
#pragma unroll
    for (int m = 0; m < 4; ++m) {
      int rb = row0 + wm + m*16 + rq;
#pragma unroll
      for (int j = 0; j < 4; ++j) {
        int r = rb + j;
        if (r < Mvalid) __builtin_nontemporal_store(acc[m][n][j] + bv, &C[(long)r * ldc + col]);
      }
    }
  }
}

__global__ __launch_bounds__(256, 2) void k_gemm_fg(
    const unsigned short* __restrict__ encb,  const unsigned short* __restrict__ WeT,
    const float* __restrict__ b_enc,  float* __restrict__ f,
    const unsigned short* __restrict__ predb, const unsigned short* __restrict__ WpT,
    const float* __restrict__ b_pred, float* __restrict__ g)
{
  const unsigned short* A;  const unsigned short* Bt;
  const float* bias; float* C; int Mv;
  if (blockIdx.z == 0) { A = encb;  Bt = WeT; bias = b_enc;  C = f; Mv = M_ENC_PAD; }
  else {
    if (blockIdx.x >= M_PRED_PAD/128) return;
    A = predb; Bt = WpT; bias = b_pred; C = g; Mv = M_PRED_PAD;
  }
  gemm_body(A, Bt, bias, C, Mv, DM, blockIdx.x, blockIdx.y);
}

// ---------------------------------------------------------------------------
// Fused main kernel. Grid 938*2; BM=128, BN=512, BK=32, 512 thr = 8 waves
// (1M x 4N), wave tile 64x128 -> acc[4][8] f32x4.
// LDS shorts: [0,4096) A buf0 | [4096,8192) A buf1 |
//             [8192,24576) B buf0 | [24576,40960) B buf1      (80 KB)
// Chunk layout (16B chunks, 4 per 32-elem row): slot = (c + (r>>1)) & 3
// -> fragment ds_read_b128 spreads 2-way over banks (free).
// ---------------------------------------------------------------------------
__global__ __launch_bounds__(512, 4) void k_joint_fused(
    const float* __restrict__ f, const float* __restrict__ g,
    const unsigned short* __restrict__ Bt, const float* __restrict__ bias,
    float* __restrict__ C)
{
  __shared__ unsigned short lds[40960];

  const int bid = blockIdx.x;
  const int mt = bid >> 1, nt = bid & 1;   // n-fastest: f/g panel reuse
  const int row0 = mt * 128;
  const int t = threadIdx.x, w = t >> 6, l = t & 63;
  const int wm = w >> 2, wn = w & 3, lr = l & 15, lc = l >> 4;

  // ---- A staging: this thread owns row (t>>2), global k-chunk (t&3) ----
  int arow = row0 + (t >> 2); if (arow > M_MAIN - 1) arow = M_MAIN - 1;
  int bb  = arow / (T_*U_);
  int rem = arow - bb * (T_*U_);
  int tt  = rem / U_;
  int uu  = rem - tt * U_;
  const float* fp = f + (bb*T_ + tt) * DM + (t & 3) * 8;
  const float* gp = g + (bb*U_ + uu) * DM + (t & 3) * 8;
  const int awr = (t >> 2)*32 + (((t & 3) + ((t >> 2) >> 1)) & 3)*8;

  // ---- B staging: 4 gload_lds per wave, pre-permuted source chunk ----
  const unsigned short* gB[4];
#pragma unroll
  for (int i = 0; i < 4; ++i) {
    int br = w*64 + i*16 + (l >> 2);
    int c  = ((l & 3) - (br >> 1)) & 3;
    gB[i] = Bt + (long)(nt*512 + br) * DM + c*8;
  }

  // ---- fragment read offsets (shorts, within a buffer) ----
  int offA[4], offB[8];
#pragma unroll
  for (int m = 0; m < 4; ++m) {
    int r = wm*64 + m*16 + lr;
    offA[m] = r*32 + ((lc + (r >> 1)) & 3)*8;
  }
#pragma unroll
  for (int n = 0; n < 8; ++n) {
    int r = wn*128 + n*16 + lr;
    offB[n] = r*32 + ((lc + (r >> 1)) & 3)*8;
  }

  f32x4 acc[4][8] = {};

  // ---- prologue: stage K-step 0 into buf 0 ----
  {
    f32x4 fa0 = *(const f32x4*)(fp);
    f32x4 fa1 = *(const f32x4*)(fp + 4);
    f32x4 ga0 = *(const f32x4*)(gp);
    f32x4 ga1 = *(const f32x4*)(gp + 4);
#pragma unroll
    for (int i = 0; i < 4; ++i)
      gload_lds16(gB[i], &lds[8192 + w*2048 + i*512]);
    s16x8 v;
#pragma unroll
    for (int j = 0; j < 4; ++j) {
      v[j]   = (short)f2bf(fast_tanh(fa0[j] + ga0[j]));
      v[4+j] = (short)f2bf(fast_tanh(fa1[j] + ga1[j]));
    }
    *(s16x8*)&lds[awr] = v;
  }
  __syncthreads();

  // ---- main loop: 16 K-steps ----
#pragma unroll
  for (int kt = 0; kt < 16; ++kt) {
    const int cur = kt & 1, nxt = cur ^ 1;
    f32x4 fa0, fa1, ga0, ga1;
    if (kt < 15) {
      const float* fpk = fp + (kt+1)*32;
      const float* gpk = gp + (kt+1)*32;
      fa0 = *(const f32x4*)(fpk);
      fa1 = *(const f32x4*)(fpk + 4);
      ga0 = *(const f32x4*)(gpk);
      ga1 = *(const f32x4*)(gpk + 4);
#pragma unroll
      for (int i = 0; i < 4; ++i)
        gload_lds16(gB[i] + (kt+1)*32, &lds[8192 + nxt*16384 + w*2048 + i*512]);
    }

    s16x8 af[4], bfv[8];
#pragma unroll
    for (int m = 0; m < 4; ++m) af[m] = *(const s16x8*)&lds[cur*4096 + offA[m]];
#pragma unroll
    for (int n = 0; n < 8; ++n) bfv[n] = *(const s16x8*)&lds[8192 + cur*16384 + offB[n]];

    __builtin_amdgcn_s_setprio(1);
#pragma unroll
    for (int m = 0; m < 4; ++m)
#pragma unroll
      for (int n = 0; n < 8; ++n)
        acc[m][n] = __builtin_amdgcn_mfma_f32_16x16x32_bf16(af[m], bfv[n], acc[m][n], 0, 0, 0);
    __builtin_amdgcn_s_setprio(0);

    if (kt < 15) {
      s16x8 v;
#pragma unroll
      for (int j = 0; j < 4; ++j) {
        v[j]   = (short)f2bf(fast_tanh(fa0[j] + ga0[j]));
        v[4+j] = (short)f2bf(fast_tanh(fa1[j] + ga1[j]));
      }
      *(s16x8*)&lds[nxt*4096 + awr] = v;
    }
    __syncthreads();
  }

  // ---- epilogue: C/D layout col=lane&15, row=(lane>>4)*4+j ----
  const int rq = lc * 4;
#pragma unroll
  for (int n = 0; n < 8; ++n) {
    int col = nt*512 + wn*128 + n*16 + lr;
    float bv = bias[col];
#pragma unroll
    for (int m = 0; m < 4; ++m) {
      int rb = row0 + wm*64 + m*16 + rq;
#pragma unroll
      for (int j = 0; j < 4; ++j) {
        int r = rb + j;
        if (r < M_MAIN)
          __builtin_nontemporal_store(acc[m][n][j] + bv, &C[(long)r * VOC + col]);
      }
    }
  }
}

// ---------------------------------------------------------------------------
extern "C" void kernel_launch(void* const* d_in, const int* in_sizes, int n_in,
                              void* d_out, int out_size, void* d_ws, size_t ws_size,
                              hipStream_t stream)
{
  const float* enc    = (const float*)d_in[0];
  const float* pred   = (const float*)d_in[1];
  const float* W_enc  = (const float*)d_in[2];
  const float* b_enc  = (const float*)d_in[3];
  const float* W_pred = (const float*)d_in[4];
  const float* b_pred = (const float*)d_in[5];
  const float* W_joint= (const float*)d_in[6];
  const float* b_joint= (const float*)d_in[7];
  float* out = (float*)d_out;

  char* w = (char*)d_ws;
  unsigned short* encb  = (unsigned short*)w; w += (long)M_ENC_PAD*DM*2;
  unsigned short* predb = (unsigned short*)w; w += (long)M_PRED_PAD*DM*2;
  unsigned short* WeT   = (unsigned short*)w; w += (long)DM*DM*2;
  unsigned short* WpT   = (unsigned short*)w; w += (long)DM*DM*2;
  unsigned short* WjT   = (unsigned short*)w; w += (long)VOC*DM*2;
  float*          f     = (float*)w;          w += (long)M_ENC_PAD*DM*4;
  float*          g     = (float*)w;          w += (long)M_PRED_PAD*DM*4;

  k_cvtpad     <<<dim3(448),       dim3(256), 0, stream>>>(enc, pred, encb, predb);
  k_transpose3 <<<dim3(32, 16, 3), dim3(256), 0, stream>>>(W_enc, W_pred, W_joint, WeT, WpT, WjT);
  k_gemm_fg    <<<dim3(10, 4, 2),  dim3(256), 0, stream>>>(encb, WeT, b_enc, f, predb, WpT, b_pred, g);
  k_joint_fused<<<dim3(938*2),     dim3(512), 0, stream>>>(f, g, WjT, b_joint, out);
}

// Round 5
// 316.373 us; speedup vs baseline: 5.5088x; 5.5088x over previous
//
#include <hip/hip_runtime.h>
#include <hip/hip_bf16.h>
#include <cstdint>

// ---------------------------------------------------------------------------
// TransducerJoint: out[b,t,u,:] = tanh(f[b,t,:] + g[b,u,:]) @ W_joint + b_joint
// R4 -> R5: fix the spill disaster. Fused main kernel kept, but:
//   * BN 512 -> 256 (acc[4][4]=64 regs -> AGPRs; tanh recompute x4)
//   * tanh phase BEFORE the MFMA cluster (f32x4 temps don't coexist with
//     the 32 fragment VGPRs) -> peak ~62 VGPR + 64 AGPR = fits 128 total
//   * launch_bounds(512,4): 2 blocks/CU (16 waves) co-resident; their
//     MFMA/VALU/LDS phases overlap across blocks (m114)
// LDS 48KB: A 2x8KB double-buf (ds_write from regs), B 2x16KB (global_load_lds,
// pre-permuted source chunks; slot = (c + (r>>1)) & 3 conflict-free layout).
// ---------------------------------------------------------------------------

typedef __attribute__((ext_vector_type(4))) float f32x4;
typedef __attribute__((ext_vector_type(8))) short s16x8;

#define B_ 4
#define T_ 300
#define U_ 100
#define DM 512
#define VOC 1024
#define M_MAIN (B_*T_*U_)       // 120000
#define M_ENC_PAD 1280          // 10 * 128 (valid 1200)
#define M_PRED_PAD 512          // 4 * 128 (valid 400)

__device__ __forceinline__ unsigned short f2bf(float x) {
  unsigned int u = __builtin_bit_cast(unsigned int, x);
  u += 0x7FFFu + ((u >> 16) & 1u);          // round-to-nearest-even
  return (unsigned short)(u >> 16);
}

__device__ __forceinline__ float fast_tanh(float x) {
  float e = __builtin_amdgcn_exp2f(x * 2.8853900817779268f);
  return fmaf(-2.0f, __builtin_amdgcn_rcpf(e + 1.0f), 1.0f);
}

__device__ __forceinline__ void gload_lds16(const void* g, void* l) {
  __builtin_amdgcn_global_load_lds(
      (const __attribute__((address_space(1))) void*)g,
      (__attribute__((address_space(3))) void*)l, 16, 0, 0);
}

// ---------------------------------------------------------------------------
__global__ void k_cvtpad(const float* __restrict__ enc, const float* __restrict__ pred,
                         unsigned short* __restrict__ encb, unsigned short* __restrict__ predb)
{
  int idx = blockIdx.x * 256 + threadIdx.x;
  const int encCh = M_ENC_PAD * 64;
  const float* src; unsigned short* dst; int Mv; int id2;
  if (idx < encCh) { src = enc; dst = encb; Mv = B_*T_; id2 = idx; }
  else            { id2 = idx - encCh; src = pred; dst = predb; Mv = B_*U_; }
  int r = id2 >> 6, k = (id2 & 63) * 8;
  s16x8 v;
  if (r < Mv) {
    f32x4 a = *(const f32x4*)(src + r*DM + k);
    f32x4 b = *(const f32x4*)(src + r*DM + k + 4);
#pragma unroll
    for (int j = 0; j < 4; ++j) { v[j] = (short)f2bf(a[j]); v[4+j] = (short)f2bf(b[j]); }
  } else {
#pragma unroll
    for (int j = 0; j < 8; ++j) v[j] = 0;
  }
  *(s16x8*)(dst + (long)id2 * 8) = v;
}

// ---------------------------------------------------------------------------
__global__ void k_transpose3(const float* __restrict__ We, const float* __restrict__ Wp,
                             const float* __restrict__ Wj,
                             unsigned short* __restrict__ WeT, unsigned short* __restrict__ WpT,
                             unsigned short* __restrict__ WjT)
{
  __shared__ float tile[32][33];
  const float* src; unsigned short* dst; int Ccols;
  const int R = 512;
  if (blockIdx.z == 0)      { src = We; dst = WeT; Ccols = 512; }
  else if (blockIdx.z == 1) { src = Wp; dst = WpT; Ccols = 512; }
  else                      { src = Wj; dst = WjT; Ccols = 1024; }
  int bx = blockIdx.x, by = blockIdx.y;
  if (bx * 32 >= Ccols) return;
  int x = threadIdx.x & 31, y = threadIdx.x >> 5;
  int c0 = bx * 32, r0 = by * 32;
#pragma unroll
  for (int i = 0; i < 4; ++i)
    tile[y + i*8][x] = src[(r0 + y + i*8) * Ccols + c0 + x];
  __syncthreads();
#pragma unroll
  for (int i = 0; i < 4; ++i)
    dst[(c0 + y + i*8) * R + r0 + x] = f2bf(tile[x][y + i*8]);
}

// ---------------------------------------------------------------------------
// 128x128 gemm body (small f/g GEMMs only).
// ---------------------------------------------------------------------------
__device__ __forceinline__ void gemm_body(const unsigned short* __restrict__ A,
                                          const unsigned short* __restrict__ Bt,
                                          const float* __restrict__ bias,
                                          float* __restrict__ C,
                                          int Mvalid, int ldc, int mt, int nt)
{
  __shared__ unsigned short lza[128*64];
  __shared__ unsigned short lzb[128*64];
  const int tid  = threadIdx.x;
  const int wave = tid >> 6;
  const int lane = tid & 63;
  const int row0 = mt * 128;
  const int col0 = nt * 128;
  const int wm = (wave >> 1) * 64;
  const int wn = (wave & 1) * 64;

  const int rloc0 = wave*32 + (lane >> 3);
  const int srcc  = (lane & 7) ^ (rloc0 & 7);
  const unsigned short* gA = A  + (row0 + rloc0)*DM + srcc*8;
  const unsigned short* gB = Bt + (col0 + rloc0)*DM + srcc*8;
  unsigned short* ldsA = &lza[(wave*32)*64];
  unsigned short* ldsB = &lzb[(wave*32)*64];

  f32x4 acc[4][4] = {};

  for (int kt = 0; kt < DM/64; ++kt) {
    __syncthreads();
#pragma unroll
    for (int i = 0; i < 4; ++i) {
      gload_lds16(gA + i*8*DM, ldsA + i*8*64);
      gload_lds16(gB + i*8*DM, ldsB + i*8*64);
    }
    gA += 64; gB += 64;
    __syncthreads();
#pragma unroll
    for (int kk = 0; kk < 2; ++kk) {
      s16x8 af[4], bfr[4];
#pragma unroll
      for (int m = 0; m < 4; ++m) {
        int r = wm + m*16 + (lane & 15);
        int c = (kk*4 + (lane >> 4)) ^ (r & 7);
        af[m] = *(const s16x8*)&lza[r*64 + c*8];
      }
#pragma unroll
      for (int n = 0; n < 4; ++n) {
        int r = wn + n*16 + (lane & 15);
        int c = (kk*4 + (lane >> 4)) ^ (r & 7);
        bfr[n] = *(const s16x8*)&lzb[r*64 + c*8];
      }
#pragma unroll
      for (int m = 0; m < 4; ++m)
#pragma unroll
        for (int n = 0; n < 4; ++n)
          acc[m][n] = __builtin_amdgcn_mfma_f32_16x16x32_bf16(af[m], bfr[n], acc[m][n], 0, 0, 0);
    }
  }

  const int cl = lane & 15, rq = (lane >> 4) * 4;
#pragma unroll
  for (int n = 0; n < 4; ++n) {
    int col = col0 + wn + n*16 + cl;
    float bv = bias[col];
#pragma unroll
    for (int m = 0; m < 4; ++m) {
      int rb = row0 + wm + m*16 + rq;
#pragma unroll
      for (int j = 0; j < 4; ++j) {
        int r = rb + j;
        if (r < Mvalid) __builtin_nontemporal_store(acc[m][n][j] + bv, &C[(long)r * ldc + col]);
      }
    }
  }
}

__global__ __launch_bounds__(256, 2) void k_gemm_fg(
    const unsigned short* __restrict__ encb,  const unsigned short* __restrict__ WeT,
    const float* __restrict__ b_enc,  float* __restrict__ f,
    const unsigned short* __restrict__ predb, const unsigned short* __restrict__ WpT,
    const float* __restrict__ b_pred, float* __restrict__ g)
{
  const unsigned short* A;  const unsigned short* Bt;
  const float* bias; float* C; int Mv;
  if (blockIdx.z == 0) { A = encb;  Bt = WeT; bias = b_enc;  C = f; Mv = M_ENC_PAD; }
  else {
    if (blockIdx.x >= M_PRED_PAD/128) return;
    A = predb; Bt = WpT; bias = b_pred; C = g; Mv = M_PRED_PAD;
  }
  gemm_body(A, Bt, bias, C, Mv, DM, blockIdx.x, blockIdx.y);
}

// ---------------------------------------------------------------------------
// Fused main kernel. BM=128, BN=256, BK=32, 512 thr = 8 waves (2M x 4N),
// wave tile 64x64 -> acc[4][4] (AGPRs). Grid 938*4, n-fastest.
// LDS shorts: [0,8192) A bufs x2 (4096 each) | [8192,24576) B bufs x2 (8192).
// Chunk layout: 16B slot = (c + (r>>1)) & 3  (conflict-free frag reads).
// Per K-step: issue B gload_lds(nxt) -> load f/g + tanh + ds_write A(nxt)
// -> frag reads(cur) -> 16 MFMA -> barrier. Cross-block overlap hides the
// serial phases (2 blocks/CU).
// ---------------------------------------------------------------------------
__global__ __launch_bounds__(512, 4) void k_joint_fused(
    const float* __restrict__ f, const float* __restrict__ g,
    const unsigned short* __restrict__ Bt, const float* __restrict__ bias,
    float* __restrict__ C)
{
  __shared__ unsigned short lds[24576];   // 48 KB

  const int bid = blockIdx.x;
  const int mt = bid >> 2, nt = bid & 3;   // n-fastest
  const int row0 = mt * 128;
  const int t = threadIdx.x, w = t >> 6, l = t & 63;
  const int wm = w >> 2, wn = w & 3, lr = l & 15, lc = l >> 4;

  // ---- A staging ownership: row t>>2 (0..127), global k-chunk t&3 ----
  int arow = row0 + (t >> 2); if (arow >= M_MAIN) arow = M_MAIN - 1;
  int bb  = arow / (T_*U_);
  int rem = arow - bb * (T_*U_);
  int tt  = rem / U_;
  int uu  = rem - tt * U_;
  const float* fp = f + (bb*T_ + tt) * DM + (t & 3) * 8;
  const float* gp = g + (bb*U_ + uu) * DM + (t & 3) * 8;
  const int awr = (t >> 2)*32 + (((t & 3) + ((t >> 2) >> 1)) & 3)*8;  // shorts

  // ---- B staging: 2 gload_lds/thread; chunk ch=(i*8+w)*64+l, linear dest ----
  const unsigned short* gBs[2];
#pragma unroll
  for (int i = 0; i < 2; ++i) {
    int ch = (i*8 + w)*64 + l;
    int br = ch >> 2;                              // B row (C col) 0..255
    int cg = ((ch & 3) - ((ch >> 3) & 3)) & 3;     // pre-permuted source chunk
    gBs[i] = Bt + (long)(nt*256 + br) * DM + cg*8;
  }

  // ---- fragment read offsets (shorts, within a buffer) ----
  int offA[4], offB[4];
#pragma unroll
  for (int m = 0; m < 4; ++m) {
    int r = wm*64 + m*16 + lr;
    offA[m] = r*32 + ((lc + (r >> 1)) & 3)*8;
  }
#pragma unroll
  for (int n = 0; n < 4; ++n) {
    int r = wn*64 + n*16 + lr;
    offB[n] = r*32 + ((lc + (r >> 1)) & 3)*8;
  }

  f32x4 acc[4][4] = {};

  // ---- prologue: stage K-step 0 into buf 0 ----
  {
#pragma unroll
    for (int i = 0; i < 2; ++i)
      gload_lds16(gBs[i], &lds[8192 + (i*8 + w)*512]);
    f32x4 fa0 = *(const f32x4*)(fp);
    f32x4 fa1 = *(const f32x4*)(fp + 4);
    f32x4 ga0 = *(const f32x4*)(gp);
    f32x4 ga1 = *(const f32x4*)(gp + 4);
    s16x8 v;
#pragma unroll
    for (int j = 0; j < 4; ++j) {
      v[j]   = (short)f2bf(fast_tanh(fa0[j] + ga0[j]));
      v[4+j] = (short)f2bf(fast_tanh(fa1[j] + ga1[j]));
    }
    *(s16x8*)&lds[awr] = v;
  }
  __syncthreads();

  // ---- main loop: 16 K-steps ----
#pragma unroll
  for (int kt = 0; kt < 16; ++kt) {
    const int cur = kt & 1, nxt = cur ^ 1;

    if (kt < 15) {
      // B prefetch for kt+1 (latency hidden under tanh + MFMA below)
#pragma unroll
      for (int i = 0; i < 2; ++i)
        gload_lds16(gBs[i] + (kt+1)*32, &lds[8192 + nxt*8192 + (i*8 + w)*512]);
      // A build for kt+1 (temps die before fragment reads -> low VGPR peak)
      {
        const float* fpk = fp + (kt+1)*32;
        const float* gpk = gp + (kt+1)*32;
        f32x4 fa0 = *(const f32x4*)(fpk);
        f32x4 fa1 = *(const f32x4*)(fpk + 4);
        f32x4 ga0 = *(const f32x4*)(gpk);
        f32x4 ga1 = *(const f32x4*)(gpk + 4);
        s16x8 v;
#pragma unroll
        for (int j = 0; j < 4; ++j) {
          v[j]   = (short)f2bf(fast_tanh(fa0[j] + ga0[j]));
          v[4+j] = (short)f2bf(fast_tanh(fa1[j] + ga1[j]));
        }
        *(s16x8*)&lds[nxt*4096 + awr] = v;
      }
    }

    s16x8 af[4], bfv[4];
#pragma unroll
    for (int m = 0; m < 4; ++m) af[m] = *(const s16x8*)&lds[cur*4096 + offA[m]];
#pragma unroll
    for (int n = 0; n < 4; ++n) bfv[n] = *(const s16x8*)&lds[8192 + cur*8192 + offB[n]];

    __builtin_amdgcn_s_setprio(1);
#pragma unroll
    for (int m = 0; m < 4; ++m)
#pragma unroll
      for (int n = 0; n < 4; ++n)
        acc[m][n] = __builtin_amdgcn_mfma_f32_16x16x32_bf16(af[m], bfv[n], acc[m][n], 0, 0, 0);
    __builtin_amdgcn_s_setprio(0);

    __syncthreads();
  }

  // ---- epilogue: C/D layout col=lane&15, row=(lane>>4)*4+j ----
  const int rq = lc * 4;
#pragma unroll
  for (int n = 0; n < 4; ++n) {
    int col = nt*256 + wn*64 + n*16 + lr;
    float bv = bias[col];
#pragma unroll
    for (int m = 0; m < 4; ++m) {
      int rb = row0 + wm*64 + m*16 + rq;
#pragma unroll
      for (int j = 0; j < 4; ++j) {
        int r = rb + j;
        if (r < M_MAIN)
          __builtin_nontemporal_store(acc[m][n][j] + bv, &C[(long)r * VOC + col]);
      }
    }
  }
}

// ---------------------------------------------------------------------------
extern "C" void kernel_launch(void* const* d_in, const int* in_sizes, int n_in,
                              void* d_out, int out_size, void* d_ws, size_t ws_size,
                              hipStream_t stream)
{
  const float* enc    = (const float*)d_in[0];
  const float* pred   = (const float*)d_in[1];
  const float* W_enc  = (const float*)d_in[2];
  const float* b_enc  = (const float*)d_in[3];
  const float* W_pred = (const float*)d_in[4];
  const float* b_pred = (const float*)d_in[5];
  const float* W_joint= (const float*)d_in[6];
  const float* b_joint= (const float*)d_in[7];
  float* out = (float*)d_out;

  char* w = (char*)d_ws;
  unsigned short* encb  = (unsigned short*)w; w += (long)M_ENC_PAD*DM*2;
  unsigned short* predb = (unsigned short*)w; w += (long)M_PRED_PAD*DM*2;
  unsigned short* WeT   = (unsigned short*)w; w += (long)DM*DM*2;
  unsigned short* WpT   = (unsigned short*)w; w += (long)DM*DM*2;
  unsigned short* WjT   = (unsigned short*)w; w += (long)VOC*DM*2;
  float*          f     = (float*)w;          w += (long)M_ENC_PAD*DM*4;
  float*          g     = (float*)w;          w += (long)M_PRED_PAD*DM*4;

  k_cvtpad     <<<dim3(448),       dim3(256), 0, stream>>>(enc, pred, encb, predb);
  k_transpose3 <<<dim3(32, 16, 3), dim3(256), 0, stream>>>(W_enc, W_pred, W_joint, WeT, WpT, WjT);
  k_gemm_fg    <<<dim3(10, 4, 2),  dim3(256), 0, stream>>>(encb, WeT, b_enc, f, predb, WpT, b_pred, g);
  k_joint_fused<<<dim3(938*4),     dim3(512), 0, stream>>>(f, g, WjT, b_joint, out);
}

// Round 6
// 295.692 us; speedup vs baseline: 5.8941x; 1.0699x over previous
//
#include <hip/hip_runtime.h>
#include <hip/hip_bf16.h>
#include <cstdint>

// ---------------------------------------------------------------------------
// TransducerJoint: out[b,t,u,:] = tanh(f[b,t,:] + g[b,u,:]) @ W_joint + b_joint
// R5 -> R6: kill the per-K-step global->register->tanh latency chain.
// Structure insight: a 128-row A-panel (rows r=(b,t,u), u fastest) touches
// only <=3 distinct f rows and <=100 distinct g rows. So stage f/g as RAW F32
// via global_load_lds (wave never blocks), distance-2 ahead of the MFMA that
// needs them; tanh reads LDS f32 (fast), packs bf16, ds_writes A one step
// ahead. All global traffic is gload_lds; the single per-iteration barrier
// drains loads issued ~1 iteration earlier. Grid aligned per-b (235 j x 4 b)
// so no block crosses a b boundary.
//  LDS (bytes): A 2x8192 | B 2x16384 | g(f32) 2x12800 | f(f32) 2x512 = 74 KB
//  -> 2 blocks/CU. acc[4][4]->AGPR, VGPR ~60.
// Swizzles: A/B 16B-slot rotate (R5, measured 0 conflicts); g chunk-rotate
// slot=(q+u)&7 -> reads hit 8 words/bank = floor (conflict-free); f broadcast.
// ---------------------------------------------------------------------------

typedef __attribute__((ext_vector_type(4))) float f32x4;
typedef __attribute__((ext_vector_type(8))) short s16x8;

#define B_ 4
#define T_ 300
#define U_ 100
#define DM 512
#define VOC 1024
#define M_MAIN (B_*T_*U_)       // 120000
#define M_ENC_PAD 1280          // 10 * 128 (valid 1200)
#define M_PRED_PAD 512          // 4 * 128 (valid 400)

__device__ __forceinline__ unsigned short f2bf(float x) {
  unsigned int u = __builtin_bit_cast(unsigned int, x);
  u += 0x7FFFu + ((u >> 16) & 1u);          // round-to-nearest-even
  return (unsigned short)(u >> 16);
}

__device__ __forceinline__ float fast_tanh(float x) {
  float e = __builtin_amdgcn_exp2f(x * 2.8853900817779268f);
  return fmaf(-2.0f, __builtin_amdgcn_rcpf(e + 1.0f), 1.0f);
}

__device__ __forceinline__ void gload_lds16(const void* g, void* l) {
  __builtin_amdgcn_global_load_lds(
      (const __attribute__((address_space(1))) void*)g,
      (__attribute__((address_space(3))) void*)l, 16, 0, 0);
}

// ---------------------------------------------------------------------------
__global__ void k_cvtpad(const float* __restrict__ enc, const float* __restrict__ pred,
                         unsigned short* __restrict__ encb, unsigned short* __restrict__ predb)
{
  int idx = blockIdx.x * 256 + threadIdx.x;
  const int encCh = M_ENC_PAD * 64;
  const float* src; unsigned short* dst; int Mv; int id2;
  if (idx < encCh) { src = enc; dst = encb; Mv = B_*T_; id2 = idx; }
  else            { id2 = idx - encCh; src = pred; dst = predb; Mv = B_*U_; }
  int r = id2 >> 6, k = (id2 & 63) * 8;
  s16x8 v;
  if (r < Mv) {
    f32x4 a = *(const f32x4*)(src + r*DM + k);
    f32x4 b = *(const f32x4*)(src + r*DM + k + 4);
#pragma unroll
    for (int j = 0; j < 4; ++j) { v[j] = (short)f2bf(a[j]); v[4+j] = (short)f2bf(b[j]); }
  } else {
#pragma unroll
    for (int j = 0; j < 8; ++j) v[j] = 0;
  }
  *(s16x8*)(dst + (long)id2 * 8) = v;
}

// ---------------------------------------------------------------------------
__global__ void k_transpose3(const float* __restrict__ We, const float* __restrict__ Wp,
                             const float* __restrict__ Wj,
                             unsigned short* __restrict__ WeT, unsigned short* __restrict__ WpT,
                             unsigned short* __restrict__ WjT)
{
  __shared__ float tile[32][33];
  const float* src; unsigned short* dst; int Ccols;
  const int R = 512;
  if (blockIdx.z == 0)      { src = We; dst = WeT; Ccols = 512; }
  else if (blockIdx.z == 1) { src = Wp; dst = WpT; Ccols = 512; }
  else                      { src = Wj; dst = WjT; Ccols = 1024; }
  int bx = blockIdx.x, by = blockIdx.y;
  if (bx * 32 >= Ccols) return;
  int x = threadIdx.x & 31, y = threadIdx.x >> 5;
  int c0 = bx * 32, r0 = by * 32;
#pragma unroll
  for (int i = 0; i < 4; ++i)
    tile[y + i*8][x] = src[(r0 + y + i*8) * Ccols + c0 + x];
  __syncthreads();
#pragma unroll
  for (int i = 0; i < 4; ++i)
    dst[(c0 + y + i*8) * R + r0 + x] = f2bf(tile[x][y + i*8]);
}

// ---------------------------------------------------------------------------
// 128x128 gemm body (small f/g GEMMs only).
// ---------------------------------------------------------------------------
__device__ __forceinline__ void gemm_body(const unsigned short* __restrict__ A,
                                          const unsigned short* __restrict__ Bt,
                                          const float* __restrict__ bias,
                                          float* __restrict__ C,
                                          int Mvalid, int ldc, int mt, int nt)
{
  __shared__ unsigned short lza[128*64];
  __shared__ unsigned short lzb[128*64];
  const int tid  = threadIdx.x;
  const int wave = tid >> 6;
  const int lane = tid & 63;
  const int row0 = mt * 128;
  const int col0 = nt * 128;
  const int wm = (wave >> 1) * 64;
  const int wn = (wave & 1) * 64;

  const int rloc0 = wave*32 + (lane >> 3);
  const int srcc  = (lane & 7) ^ (rloc0 & 7);
  const unsigned short* gA = A  + (row0 + rloc0)*DM + srcc*8;
  const unsigned short* gB = Bt + (col0 + rloc0)*DM + srcc*8;
  unsigned short* ldsA = &lza[(wave*32)*64];
  unsigned short* ldsB = &lzb[(wave*32)*64];

  f32x4 acc[4][4] = {};

  for (int kt = 0; kt < DM/64; ++kt) {
    __syncthreads();
#pragma unroll
    for (int i = 0; i < 4; ++i) {
      gload_lds16(gA + i*8*DM, ldsA + i*8*64);
      gload_lds16(gB + i*8*DM, ldsB + i*8*64);
    }
    gA += 64; gB += 64;
    __syncthreads();
#pragma unroll
    for (int kk = 0; kk < 2; ++kk) {
      s16x8 af[4], bfr[4];
#pragma unroll
      for (int m = 0; m < 4; ++m) {
        int r = wm + m*16 + (lane & 15);
        int c = (kk*4 + (lane >> 4)) ^ (r & 7);
        af[m] = *(const s16x8*)&lza[r*64 + c*8];
      }
#pragma unroll
      for (int n = 0; n < 4; ++n) {
        int r = wn + n*16 + (lane & 15);
        int c = (kk*4 + (lane >> 4)) ^ (r & 7);
        bfr[n] = *(const s16x8*)&lzb[r*64 + c*8];
      }
#pragma unroll
      for (int m = 0; m < 4; ++m)
#pragma unroll
        for (int n = 0; n < 4; ++n)
          acc[m][n] = __builtin_amdgcn_mfma_f32_16x16x32_bf16(af[m], bfr[n], acc[m][n], 0, 0, 0);
    }
  }

  const int cl = lane & 15, rq = (lane >> 4) * 4;
#pragma unroll
  for (int n = 0; n < 4; ++n) {
    int col = col0 + wn + n*16 + cl;
    float bv = bias[col];
#pragma unroll
    for (int m = 0; m < 4; ++m) {
      int rb = row0 + wm + m*16 + rq;
#pragma unroll
      for (int j = 0; j < 4; ++j) {
        int r = rb + j;
        if (r < Mvalid) __builtin_nontemporal_store(acc[m][n][j] + bv, &C[(long)r * ldc + col]);
      }
    }
  }
}

__global__ __launch_bounds__(256, 2) void k_gemm_fg(
    const unsigned short* __restrict__ encb,  const unsigned short* __restrict__ WeT,
    const float* __restrict__ b_enc,  float* __restrict__ f,
    const unsigned short* __restrict__ predb, const unsigned short* __restrict__ WpT,
    const float* __restrict__ b_pred, float* __restrict__ g)
{
  const unsigned short* A;  const unsigned short* Bt;
  const float* bias; float* C; int Mv;
  if (blockIdx.z == 0) { A = encb;  Bt = WeT; bias = b_enc;  C = f; Mv = M_ENC_PAD; }
  else {
    if (blockIdx.x >= M_PRED_PAD/128) return;
    A = predb; Bt = WpT; bias = b_pred; C = g; Mv = M_PRED_PAD;
  }
  gemm_body(A, Bt, bias, C, Mv, DM, blockIdx.x, blockIdx.y);
}

// ---------------------------------------------------------------------------
// Fused main kernel. Grid (4 nt, 235 j, 4 b), 512 thr = 8 waves (2M x 4N),
// BM=128 (rows j*128..+127 within batch b), BN=256, BK=32.
// smem byte map:
//   Abuf(v) = v*8192            bf16 [128][32], slot=(c+(i>>1))&3
//   Bbuf(v) = 16384 + v*16384   bf16 [256][32], slot=(c+(r>>1))&3
//   gbuf(v) = 49152 + v*12800   f32  [100][32], chunk slot=(q+u)&7
//   fbuf(v) = 74752 + v*512     f32  [4][32],   chunk slot=(q-jf)... rotate
// Per iter kt: stage B[kt+1]->Bbuf[nxt], g/f[kt+2]->g/fbuf[cur] (gload_lds);
// BUILD_A(kt+1): LDS f32 reads + tanh + pack -> Abuf[nxt]; frag reads cur;
// 16 MFMA (setprio); one __syncthreads (drains loads issued ~1 iter ago).
// ---------------------------------------------------------------------------
__global__ __launch_bounds__(512, 4) void k_joint_fused(
    const float* __restrict__ f, const float* __restrict__ g,
    const unsigned short* __restrict__ Bt, const float* __restrict__ bias,
    float* __restrict__ C)
{
  __shared__ char smem[75776];

  const int nt = blockIdx.x;            // 0..3
  const int jb = blockIdx.y;            // 0..234
  const int b  = blockIdx.z;            // 0..3
  const int t = threadIdx.x, w = t >> 6, l = t & 63;
  const int wm = w >> 2, wn = w & 3, lr = l & 15, lc = l >> 4;

  // ---- A-build constants: thread owns A-row i, 8-float chunk c ----
  const int i = t >> 2, c = t & 3;
  int lcl = jb*128 + i; if (lcl > T_*U_ - 1) lcl = T_*U_ - 1;
  const int u  = lcl % U_;
  const int tl = lcl / U_;
  const int bt0l = (jb*128) / U_;
  const int jf = tl - bt0l;                                  // 0..2
  const int goff0 = u*128 + (((2*c    ) + u) & 7)*16;        // within gbuf
  const int goff1 = u*128 + (((2*c + 1) + u) & 7)*16;
  const int foff0 = jf*128 + (((2*c    ) + jf) & 7)*16;      // within fbuf
  const int foff1 = jf*128 + (((2*c + 1) + jf) & 7)*16;
  const int awr   = i*64 + ((c + (i >> 1)) & 3)*16;          // within Abuf

  // ---- B staging (2 slots/thread), pre-permuted source chunk ----
  const unsigned short* gBs[2]; int Bdst[2];
#pragma unroll
  for (int s = 0; s < 2; ++s) {
    int ch = (s*8 + w)*64 + l;
    int br = ch >> 2;
    int cg = ((ch & 3) - ((ch >> 3) & 3)) & 3;
    gBs[s] = Bt + (long)(nt*256 + br) * DM + cg*8;
    Bdst[s] = (s*8 + w)*1024;                                // within Bbuf
  }
  // ---- g staging: round A (all threads), round B (t<288) ----
  const int chA = w*64 + l;
  const float* gsrcA = g + (long)(b*U_ + (chA >> 3)) * DM + (((chA & 7) - (chA >> 3)) & 7)*4;
  const int gdstA = w*1024;
  const int chB2 = 512 + w*64 + l;
  const float* gsrcB = g + (long)(b*U_ + (chB2 >> 3)) * DM + (((chB2 & 7) - (chB2 >> 3)) & 7)*4;
  const int gdstB = 8192 + w*1024;
  // ---- f staging: threads 448..479 (wave 7 lanes 0..31), 32 chunks ----
  const bool isF = (t >= 448 && t < 480);
  int frow = bt0l + (l >> 3); if (frow > T_ - 1) frow = T_ - 1;
  const float* fsrc = f + (long)(b*T_ + frow) * DM + (((l & 7) - (l >> 3)) & 7)*4;

  // ---- fragment read offsets (bytes within A/B buffer) ----
  int offA[4], offB[4];
#pragma unroll
  for (int m = 0; m < 4; ++m) {
    int r = wm*64 + m*16 + lr;
    offA[m] = r*64 + ((lc + (r >> 1)) & 3)*16;
  }
#pragma unroll
  for (int n = 0; n < 4; ++n) {
    int r = wn*64 + n*16 + lr;
    offB[n] = r*64 + ((lc + (r >> 1)) & 3)*16;
  }

#define STAGE_B(kt_, v_) { \
    gload_lds16(gBs[0] + (kt_)*32, smem + 16384 + (v_)*16384 + Bdst[0]); \
    gload_lds16(gBs[1] + (kt_)*32, smem + 16384 + (v_)*16384 + Bdst[1]); }
#define STAGE_GF(kt_, v_) { \
    gload_lds16(gsrcA + (kt_)*32, smem + 49152 + (v_)*12800 + gdstA); \
    if (t < 288) gload_lds16(gsrcB + (kt_)*32, smem + 49152 + (v_)*12800 + gdstB); \
    if (isF)     gload_lds16(fsrc  + (kt_)*32, smem + 74752 + (v_)*512); }
#define BUILD_A(v_) { \
    f32x4 ga0 = *(const f32x4*)(smem + 49152 + (v_)*12800 + goff0); \
    f32x4 ga1 = *(const f32x4*)(smem + 49152 + (v_)*12800 + goff1); \
    f32x4 fa0 = *(const f32x4*)(smem + 74752 + (v_)*512 + foff0); \
    f32x4 fa1 = *(const f32x4*)(smem + 74752 + (v_)*512 + foff1); \
    s16x8 v; \
    _Pragma("unroll") \
    for (int jj = 0; jj < 4; ++jj) { \
      v[jj]   = (short)f2bf(fast_tanh(fa0[jj] + ga0[jj])); \
      v[4+jj] = (short)f2bf(fast_tanh(fa1[jj] + ga1[jj])); \
    } \
    *(s16x8*)(smem + (v_)*8192 + awr) = v; }

  f32x4 acc[4][4] = {};

  // ---- prologue ----
  STAGE_B(0, 0); STAGE_GF(0, 0);
  __syncthreads();
  STAGE_GF(1, 1);
  BUILD_A(0);
  __syncthreads();

  // ---- main loop: 16 K-steps, one barrier each ----
#pragma unroll
  for (int kt = 0; kt < 16; ++kt) {
    const int cur = kt & 1, nxt = cur ^ 1;
    if (kt < 15) STAGE_B(kt + 1, nxt);
    if (kt < 14) STAGE_GF(kt + 2, cur);
    if (kt < 15) BUILD_A(nxt);

    s16x8 af[4], bfv[4];
#pragma unroll
    for (int m = 0; m < 4; ++m) af[m] = *(const s16x8*)(smem + cur*8192 + offA[m]);
#pragma unroll
    for (int n = 0; n < 4; ++n) bfv[n] = *(const s16x8*)(smem + 16384 + cur*16384 + offB[n]);

    __builtin_amdgcn_s_setprio(1);
#pragma unroll
    for (int m = 0; m < 4; ++m)
#pragma unroll
      for (int n = 0; n < 4; ++n)
        acc[m][n] = __builtin_amdgcn_mfma_f32_16x16x32_bf16(af[m], bfv[n], acc[m][n], 0, 0, 0);
    __builtin_amdgcn_s_setprio(0);

    if (kt < 15) __syncthreads();
  }

  // ---- epilogue: C/D layout col=lane&15, row=(lane>>4)*4+j ----
  const int rq = lc * 4;
#pragma unroll
  for (int n = 0; n < 4; ++n) {
    int col = nt*256 + wn*64 + n*16 + lr;
    float bv = bias[col];
#pragma unroll
    for (int m = 0; m < 4; ++m) {
      int rl = jb*128 + wm*64 + m*16 + rq;
#pragma unroll
      for (int j2 = 0; j2 < 4; ++j2) {
        int rowl = rl + j2;
        if (rowl < T_*U_)
          __builtin_nontemporal_store(acc[m][n][j2] + bv,
                                      &C[(long)(b*(T_*U_) + rowl) * VOC + col]);
      }
    }
  }
#undef STAGE_B
#undef STAGE_GF
#undef BUILD_A
}

// ---------------------------------------------------------------------------
extern "C" void kernel_launch(void* const* d_in, const int* in_sizes, int n_in,
                              void* d_out, int out_size, void* d_ws, size_t ws_size,
                              hipStream_t stream)
{
  const float* enc    = (const float*)d_in[0];
  const float* pred   = (const float*)d_in[1];
  const float* W_enc  = (const float*)d_in[2];
  const float* b_enc  = (const float*)d_in[3];
  const float* W_pred = (const float*)d_in[4];
  const float* b_pred = (const float*)d_in[5];
  const float* W_joint= (const float*)d_in[6];
  const float* b_joint= (const float*)d_in[7];
  float* out = (float*)d_out;

  char* w = (char*)d_ws;
  unsigned short* encb  = (unsigned short*)w; w += (long)M_ENC_PAD*DM*2;
  unsigned short* predb = (unsigned short*)w; w += (long)M_PRED_PAD*DM*2;
  unsigned short* WeT   = (unsigned short*)w; w += (long)DM*DM*2;
  unsigned short* WpT   = (unsigned short*)w; w += (long)DM*DM*2;
  unsigned short* WjT   = (unsigned short*)w; w += (long)VOC*DM*2;
  float*          f     = (float*)w;          w += (long)M_ENC_PAD*DM*4;
  float*          g     = (float*)w;          w += (long)M_PRED_PAD*DM*4;

  k_cvtpad     <<<dim3(448),       dim3(256), 0, stream>>>(enc, pred, encb, predb);
  k_transpose3 <<<dim3(32, 16, 3), dim3(256), 0, stream>>>(W_enc, W_pred, W_joint, WeT, WpT, WjT);
  k_gemm_fg    <<<dim3(10, 4, 2),  dim3(256), 0, stream>>>(encb, WeT, b_enc, f, predb, WpT, b_pred, g);
  k_joint_fused<<<dim3(4, 235, 4), dim3(512), 0, stream>>>(f, g, WjT, b_joint, out);
}